// Round 2
// baseline (319.831 us; speedup 1.0000x reference)
//
#include <hip/hip_runtime.h>
#include <math.h>

// B=4, N=128, H=W=32, C=64.  out[b][j][n] = sigmoid(wl[j,:] . mean_hw MLP(...) + bl[j])
//
// R10: REGISTER-CHAINED ACTIVATIONS, LDS-RESIDENT WEIGHTS, 4 WAVES/EU.
// R9 post-mortem: the 16x16x16 layout-match chaining (C/D row=(lane>>4)*4+reg
// == B k=(lane>>4)*4+j -> acc IS next layer's B-frag, zero LDS/shuffle for
// activations) is correct, but hoisting all weights into 128 VGPRs spilled:
// WRITE_SIZE 48B -> 13.4MB scratch, VGPR capped 128, kernel 30 -> 62us.
// Fixes, traffic-neutral:
//   1. Weights STAY in LDS (already staged); per layer 16x ds_read_b64
//      A-frags. DS pipe is idle now (activations never touch LDS), 2-way
//      bank aliasing = free. Peak pressure ~100 VGPR -> no spill at 128 cap.
//   2. Occupancy 2 -> 4 waves/EU: 512-thread blocks (8 waves x 128 px),
//      POOL shrunk 16KB -> 2KB via in-wave shfl_xor pre-reduction over the
//      16 pixel-columns. LDS ~36KB, grid 512 = 2 blocks/CU = 16 waves/CU.
//      4/EU is the VGPR-allowed max (<=128) -> __launch_bounds__(512,4).
// Tripwires: WRITE_SIZE back to ~KB; VGPR<=128 with no scratch.

typedef float  f32x4  __attribute__((ext_vector_type(4)));
typedef f32x4  f32x4a __attribute__((may_alias));
typedef __bf16 bf16x4 __attribute__((ext_vector_type(4)));
typedef bf16x4 bf16x4a __attribute__((may_alias));
typedef short  s16x4  __attribute__((ext_vector_type(4)));

static __device__ __forceinline__ f32x4 MFMA16(bf16x4 a, bf16x4 b, f32x4 c) {
    return __builtin_amdgcn_mfma_f32_16x16x16bf16_1k(
        __builtin_bit_cast(s16x4, a), __builtin_bit_cast(s16x4, b), c, 0, 0, 0);
}

static __device__ __forceinline__ bf16x4 cvt4(f32x4 v) {
    bf16x4 r;
    r[0] = (__bf16)v[0]; r[1] = (__bf16)v[1];
    r[2] = (__bf16)v[2]; r[3] = (__bf16)v[3];
    return r;
}

__global__ __launch_bounds__(512, 4) void mlp_mfma_kernel(
    const float* __restrict__ image,   // [4,3,32,32]
    const float* __restrict__ coords,  // [4,128,2]
    const float* __restrict__ w1, const float* __restrict__ b1,   // [64,7],[64]
    const float* __restrict__ w2, const float* __restrict__ b2,   // [64,64],[64]
    const float* __restrict__ w3, const float* __restrict__ b3,
    const float* __restrict__ w4, const float* __restrict__ b4,
    const float* __restrict__ w5, const float* __restrict__ b5,
    const float* __restrict__ wl, const float* __restrict__ bl,   // [3,64],[3]
    float* __restrict__ out)           // [4,3,128]
{
    // WF: [l][frag=mt*4+ks][lane] x bf16x4  = 4*16*64*4 bf16 = 32 KB
    __shared__ __align__(16) __bf16 WF[16384];
    __shared__ __align__(16) float  POOL[8][64];     // [wave][ch]  2 KB
    __shared__ float BL[320];                        // [layer][64]

    const int tid  = threadIdx.x;
    const int wave = tid >> 6;
    const int lane = tid & 63;
    const int c15  = lane & 15;
    const int q    = lane >> 4;
    const int bn   = blockIdx.x;
    const int b    = bn >> 7;

    const float* Ws[4] = {w2, w3, w4, w5};

    // ---- stage weight A-frags (bf16) into LDS: wave w -> layer w>>1,
    // frags (w&1)*8 .. +8.  Frag (mt,ks): lane holds W[mt*16+c15][ks*16+4q+j].
    {
        const int l  = wave >> 1;
        const int f0 = (wave & 1) * 8;
        const float* Wsrc = Ws[l];
        #pragma unroll
        for (int i = 0; i < 8; ++i) {
            const int f  = f0 + i;
            const int mt = f >> 2, ks = f & 3;
            f32x4 v = *(const f32x4a*)(Wsrc + (mt * 16 + c15) * 64 + ks * 16 + 4 * q);
            *(bf16x4a*)&WF[((l * 16 + f) * 64 + lane) * 4] = cvt4(v);
        }
    }
    if (tid < 64) {
        BL[tid]       = b1[tid];
        BL[64 + tid]  = b2[tid];
        BL[128 + tid] = b3[tid];
        BL[192 + tid] = b4[tid];
        BL[256 + tid] = b5[tid];
    }
    __syncthreads();

    // ---- layer-1 A-frags (K=16, channels 0..6 used): w1[row][k], k=4q+j
    bf16x4 a1[4];
    #pragma unroll
    for (int mt = 0; mt < 4; ++mt)
        #pragma unroll
        for (int j = 0; j < 4; ++j) {
            const int k = 4 * q + j;
            float v = (k < 7) ? w1[(mt * 16 + c15) * 7 + k] : 0.0f;
            a1[mt][j] = (__bf16)v;
        }

    const float cx = coords[2 * bn + 0];
    const float cy = coords[2 * bn + 1];
    const float* img = image + b * 3072;

    // ---- loop-invariant pieces of the layer-1 B-fragment.
    // B1 lane (q,c15): q=0 -> [img0,img1,img2,row], q=1 -> [col,cx,cy,0], else 0.
    const float inv31 = 1.0f / 31.0f;
    const bool  q0  = (q == 0);
    const float g0e = (q == 1) ? (float)c15 * inv31        : 0.0f;
    const float g0o = (q == 1) ? (float)(c15 + 16) * inv31 : 0.0f;
    const float g1  = (q == 1) ? cx : 0.0f;
    const float g2  = (q == 1) ? cy : 0.0f;

    f32x4 pool[4];
    #pragma unroll
    for (int mt = 0; mt < 4; ++mt) pool[mt] = (f32x4){0.f, 0.f, 0.f, 0.f};

    // prefetch pixels for tile 0 (hw = wave*128 + t*16 + c15)
    float p0, p1, p2;
    {
        const int hw = wave * 128 + c15;
        p0 = img[hw]; p1 = img[1024 + hw]; p2 = img[2048 + hw];
    }

    #pragma unroll 1
    for (int t = 0; t < 8; ++t) {       // 8 tiles x 16 px per wave
        // ---- build layer-1 B fragment from prefetched pixels
        const float rowv = (float)(wave * 4 + (t >> 1)) * inv31;
        const float f0 = q0 ? p0 : ((t & 1) ? g0o : g0e);
        const float f1 = q0 ? p1 : g1;
        const float f2 = q0 ? p2 : g2;
        const float f3 = q0 ? rowv : 0.0f;
        bf16x4 B1;
        B1[0] = (__bf16)f0; B1[1] = (__bf16)f1;
        B1[2] = (__bf16)f2; B1[3] = (__bf16)f3;

        // ---- prefetch next tile's pixels
        {
            const int tt = (t < 7) ? (t + 1) : 7;
            const int hw = wave * 128 + tt * 16 + c15;
            p0 = img[hw]; p1 = img[1024 + hw]; p2 = img[2048 + hw];
        }

        // ======== layer 1 (acc init = bias from LDS) ========
        f32x4 acc[4];
        #pragma unroll
        for (int mt = 0; mt < 4; ++mt)
            acc[mt] = *(const f32x4a*)&BL[mt * 16 + 4 * q];
        #pragma unroll
        for (int mt = 0; mt < 4; ++mt)
            acc[mt] = MFMA16(a1[mt], B1, acc[mt]);

        // ======== layers 2..5 — register-chained acts, LDS weights ========
        #pragma unroll
        for (int l = 0; l < 4; ++l) {
            // transition: leaky + cvt; acc[mt] -> B-fragment ks=mt (same lane!)
            bf16x4 Bf[4];
            #pragma unroll
            for (int mt = 0; mt < 4; ++mt) {
                f32x4 v = acc[mt];
                #pragma unroll
                for (int r = 0; r < 4; ++r) v[r] = fmaxf(v[r], 0.1f * v[r]);
                Bf[mt] = cvt4(v);
            }
            #pragma unroll
            for (int mt = 0; mt < 4; ++mt)
                acc[mt] = *(const f32x4a*)&BL[(l + 1) * 64 + mt * 16 + 4 * q];
            #pragma unroll
            for (int ks = 0; ks < 4; ++ks) {
                bf16x4 af[4];
                #pragma unroll
                for (int mt = 0; mt < 4; ++mt)
                    af[mt] = *(const bf16x4a*)
                        &WF[((l * 16 + mt * 4 + ks) * 64 + lane) * 4];
                #pragma unroll
                for (int mt = 0; mt < 4; ++mt)
                    acc[mt] = MFMA16(af[mt], Bf[ks], acc[mt]);
            }
        }

        // ---- final leaky + pool accumulate (registers only)
        #pragma unroll
        for (int mt = 0; mt < 4; ++mt)
            #pragma unroll
            for (int r = 0; r < 4; ++r) {
                const float v = acc[mt][r];
                pool[mt][r] += fmaxf(v, 0.1f * v);
            }
    }

    // ---- in-wave pre-reduce over the 16 pixel-columns (c15 bits 0..3)
    #pragma unroll
    for (int mt = 0; mt < 4; ++mt)
        #pragma unroll
        for (int r = 0; r < 4; ++r) {
            float v = pool[mt][r];
            v += __shfl_xor(v, 1, 64);
            v += __shfl_xor(v, 2, 64);
            v += __shfl_xor(v, 4, 64);
            v += __shfl_xor(v, 8, 64);
            pool[mt][r] = v;
        }
    if (c15 == 0) {
        #pragma unroll
        for (int mt = 0; mt < 4; ++mt)
            *(f32x4a*)&POOL[wave][mt * 16 + 4 * q] = pool[mt];
    }

    __syncthreads();

    // ---- block reduce (8 waves) + head + sigmoid
    if (tid < 64) {
        const int c = tid;
        float s = 0.0f;
        #pragma unroll
        for (int w = 0; w < 8; ++w) s += POOL[w][c];
        const float p = s * (1.0f / 1024.0f);
        float s0 = wl[c] * p;
        float s1 = wl[64 + c] * p;
        float s2 = wl[128 + c] * p;
        #pragma unroll
        for (int off = 32; off > 0; off >>= 1) {
            s0 += __shfl_down(s0, off, 64);
            s1 += __shfl_down(s1, off, 64);
            s2 += __shfl_down(s2, off, 64);
        }
        if (c == 0) {
            const int n = bn & 127;
            out[(b * 3 + 0) * 128 + n] = 1.0f / (1.0f + expf(-(bl[0] + s0)));
            out[(b * 3 + 1) * 128 + n] = 1.0f / (1.0f + expf(-(bl[1] + s1)));
            out[(b * 3 + 2) * 128 + n] = 1.0f / (1.0f + expf(-(bl[2] + s2)));
        }
    }
}

extern "C" void kernel_launch(void* const* d_in, const int* in_sizes, int n_in,
                              void* d_out, int out_size, void* d_ws, size_t ws_size,
                              hipStream_t stream) {
    const float* image  = (const float*)d_in[0];
    const float* coords = (const float*)d_in[1];
    const float* w1 = (const float*)d_in[2];
    const float* b1 = (const float*)d_in[3];
    const float* w2 = (const float*)d_in[4];
    const float* b2 = (const float*)d_in[5];
    const float* w3 = (const float*)d_in[6];
    const float* b3 = (const float*)d_in[7];
    const float* w4 = (const float*)d_in[8];
    const float* b4 = (const float*)d_in[9];
    const float* w5 = (const float*)d_in[10];
    const float* b5 = (const float*)d_in[11];
    const float* wl = (const float*)d_in[12];
    const float* bl = (const float*)d_in[13];
    float* out = (float*)d_out;

    mlp_mfma_kernel<<<dim3(512), dim3(512), 0, stream>>>(
        image, coords, w1, b1, w2, b2, w3, b3, w4, b4, w5, b5, wl, bl, out);
}

// Round 3
// 134.183 us; speedup vs baseline: 2.3835x; 2.3835x over previous
//
#include <hip/hip_runtime.h>
#include <math.h>

// B=4, N=128, H=W=32, C=64.  out[b][j][n] = sigmoid(wl[j,:] . mean_hw MLP(...) + bl[j])
//
// R11: FIX LAUNCH BOUNDS (R10 one-line bug). R10 post-mortem: structure
// fine (passed, 0 bank conflicts) but __launch_bounds__(512,4) acted as
// CUDA-style min-BLOCKS/CU on this toolchain: 4 blk x 8 waves / 4 SIMD =
// 8 waves/EU -> VGPR capped 64 -> ~100-VGPR working set spilled
// (FETCH 614MB, WRITE 163MB scratch, 248us).
// Fix: __launch_bounds__(512, 2): 2 blocks/CU (= the actual grid ratio,
// 512 blocks / 256 CU) -> 4 waves/EU -> 128 VGPR cap. No other changes.
// Structure (R9/R10, proven): 16x16x16 MFMA layout-match chaining --
// C/D row=(lane>>4)*4+reg == B k=(lane>>4)*4+j, so acc[mt] of layer l IS
// the ks=mt B-fragment of layer l+1 after in-register leaky+cvt. Zero
// activation LDS traffic. Weights in LDS (ds_read_b64 per frag), biases
// in LDS, image pixels prefetched one tile ahead.
// Tripwires: VGPR 96-128, WRITE_SIZE ~KB, FETCH_SIZE ~MB.

typedef float  f32x4  __attribute__((ext_vector_type(4)));
typedef f32x4  f32x4a __attribute__((may_alias));
typedef __bf16 bf16x4 __attribute__((ext_vector_type(4)));
typedef bf16x4 bf16x4a __attribute__((may_alias));
typedef short  s16x4  __attribute__((ext_vector_type(4)));

static __device__ __forceinline__ f32x4 MFMA16(bf16x4 a, bf16x4 b, f32x4 c) {
    return __builtin_amdgcn_mfma_f32_16x16x16bf16_1k(
        __builtin_bit_cast(s16x4, a), __builtin_bit_cast(s16x4, b), c, 0, 0, 0);
}

static __device__ __forceinline__ bf16x4 cvt4(f32x4 v) {
    bf16x4 r;
    r[0] = (__bf16)v[0]; r[1] = (__bf16)v[1];
    r[2] = (__bf16)v[2]; r[3] = (__bf16)v[3];
    return r;
}

__global__ __launch_bounds__(512, 2) void mlp_mfma_kernel(
    const float* __restrict__ image,   // [4,3,32,32]
    const float* __restrict__ coords,  // [4,128,2]
    const float* __restrict__ w1, const float* __restrict__ b1,   // [64,7],[64]
    const float* __restrict__ w2, const float* __restrict__ b2,   // [64,64],[64]
    const float* __restrict__ w3, const float* __restrict__ b3,
    const float* __restrict__ w4, const float* __restrict__ b4,
    const float* __restrict__ w5, const float* __restrict__ b5,
    const float* __restrict__ wl, const float* __restrict__ bl,   // [3,64],[3]
    float* __restrict__ out)           // [4,3,128]
{
    // WF: [l][frag=mt*4+ks][lane] x bf16x4  = 4*16*64*4 bf16 = 32 KB
    __shared__ __align__(16) __bf16 WF[16384];
    __shared__ __align__(16) float  POOL[8][64];     // [wave][ch]  2 KB
    __shared__ float BL[320];                        // [layer][64]

    const int tid  = threadIdx.x;
    const int wave = tid >> 6;
    const int lane = tid & 63;
    const int c15  = lane & 15;
    const int q    = lane >> 4;
    const int bn   = blockIdx.x;
    const int b    = bn >> 7;

    const float* Ws[4] = {w2, w3, w4, w5};

    // ---- stage weight A-frags (bf16) into LDS: wave w -> layer w>>1,
    // frags (w&1)*8 .. +8.  Frag (mt,ks): lane holds W[mt*16+c15][ks*16+4q+j].
    {
        const int l  = wave >> 1;
        const int f0 = (wave & 1) * 8;
        const float* Wsrc = Ws[l];
        #pragma unroll
        for (int i = 0; i < 8; ++i) {
            const int f  = f0 + i;
            const int mt = f >> 2, ks = f & 3;
            f32x4 v = *(const f32x4a*)(Wsrc + (mt * 16 + c15) * 64 + ks * 16 + 4 * q);
            *(bf16x4a*)&WF[((l * 16 + f) * 64 + lane) * 4] = cvt4(v);
        }
    }
    if (tid < 64) {
        BL[tid]       = b1[tid];
        BL[64 + tid]  = b2[tid];
        BL[128 + tid] = b3[tid];
        BL[192 + tid] = b4[tid];
        BL[256 + tid] = b5[tid];
    }
    __syncthreads();

    // ---- layer-1 A-frags (K=16, channels 0..6 used): w1[row][k], k=4q+j
    bf16x4 a1[4];
    #pragma unroll
    for (int mt = 0; mt < 4; ++mt)
        #pragma unroll
        for (int j = 0; j < 4; ++j) {
            const int k = 4 * q + j;
            float v = (k < 7) ? w1[(mt * 16 + c15) * 7 + k] : 0.0f;
            a1[mt][j] = (__bf16)v;
        }

    const float cx = coords[2 * bn + 0];
    const float cy = coords[2 * bn + 1];
    const float* img = image + b * 3072;

    // ---- loop-invariant pieces of the layer-1 B-fragment.
    // B1 lane (q,c15): q=0 -> [img0,img1,img2,row], q=1 -> [col,cx,cy,0], else 0.
    const float inv31 = 1.0f / 31.0f;
    const bool  q0  = (q == 0);
    const float g0e = (q == 1) ? (float)c15 * inv31        : 0.0f;
    const float g0o = (q == 1) ? (float)(c15 + 16) * inv31 : 0.0f;
    const float g1  = (q == 1) ? cx : 0.0f;
    const float g2  = (q == 1) ? cy : 0.0f;

    f32x4 pool[4];
    #pragma unroll
    for (int mt = 0; mt < 4; ++mt) pool[mt] = (f32x4){0.f, 0.f, 0.f, 0.f};

    // prefetch pixels for tile 0 (hw = wave*128 + t*16 + c15)
    float p0, p1, p2;
    {
        const int hw = wave * 128 + c15;
        p0 = img[hw]; p1 = img[1024 + hw]; p2 = img[2048 + hw];
    }

    #pragma unroll 1
    for (int t = 0; t < 8; ++t) {       // 8 tiles x 16 px per wave
        // ---- build layer-1 B fragment from prefetched pixels
        const float rowv = (float)(wave * 4 + (t >> 1)) * inv31;
        const float f0 = q0 ? p0 : ((t & 1) ? g0o : g0e);
        const float f1 = q0 ? p1 : g1;
        const float f2 = q0 ? p2 : g2;
        const float f3 = q0 ? rowv : 0.0f;
        bf16x4 B1;
        B1[0] = (__bf16)f0; B1[1] = (__bf16)f1;
        B1[2] = (__bf16)f2; B1[3] = (__bf16)f3;

        // ---- prefetch next tile's pixels
        {
            const int tt = (t < 7) ? (t + 1) : 7;
            const int hw = wave * 128 + tt * 16 + c15;
            p0 = img[hw]; p1 = img[1024 + hw]; p2 = img[2048 + hw];
        }

        // ======== layer 1 (acc init = bias from LDS) ========
        f32x4 acc[4];
        #pragma unroll
        for (int mt = 0; mt < 4; ++mt)
            acc[mt] = *(const f32x4a*)&BL[mt * 16 + 4 * q];
        #pragma unroll
        for (int mt = 0; mt < 4; ++mt)
            acc[mt] = MFMA16(a1[mt], B1, acc[mt]);

        // ======== layers 2..5 — register-chained acts, LDS weights ========
        #pragma unroll
        for (int l = 0; l < 4; ++l) {
            // transition: leaky + cvt; acc[mt] -> B-fragment ks=mt (same lane!)
            bf16x4 Bf[4];
            #pragma unroll
            for (int mt = 0; mt < 4; ++mt) {
                f32x4 v = acc[mt];
                #pragma unroll
                for (int r = 0; r < 4; ++r) v[r] = fmaxf(v[r], 0.1f * v[r]);
                Bf[mt] = cvt4(v);
            }
            #pragma unroll
            for (int mt = 0; mt < 4; ++mt)
                acc[mt] = *(const f32x4a*)&BL[(l + 1) * 64 + mt * 16 + 4 * q];
            #pragma unroll
            for (int ks = 0; ks < 4; ++ks) {
                bf16x4 af[4];
                #pragma unroll
                for (int mt = 0; mt < 4; ++mt)
                    af[mt] = *(const bf16x4a*)
                        &WF[((l * 16 + mt * 4 + ks) * 64 + lane) * 4];
                #pragma unroll
                for (int mt = 0; mt < 4; ++mt)
                    acc[mt] = MFMA16(af[mt], Bf[ks], acc[mt]);
            }
        }

        // ---- final leaky + pool accumulate (registers only)
        #pragma unroll
        for (int mt = 0; mt < 4; ++mt)
            #pragma unroll
            for (int r = 0; r < 4; ++r) {
                const float v = acc[mt][r];
                pool[mt][r] += fmaxf(v, 0.1f * v);
            }
    }

    // ---- in-wave pre-reduce over the 16 pixel-columns (c15 bits 0..3)
    #pragma unroll
    for (int mt = 0; mt < 4; ++mt)
        #pragma unroll
        for (int r = 0; r < 4; ++r) {
            float v = pool[mt][r];
            v += __shfl_xor(v, 1, 64);
            v += __shfl_xor(v, 2, 64);
            v += __shfl_xor(v, 4, 64);
            v += __shfl_xor(v, 8, 64);
            pool[mt][r] = v;
        }
    if (c15 == 0) {
        #pragma unroll
        for (int mt = 0; mt < 4; ++mt)
            *(f32x4a*)&POOL[wave][mt * 16 + 4 * q] = pool[mt];
    }

    __syncthreads();

    // ---- block reduce (8 waves) + head + sigmoid
    if (tid < 64) {
        const int c = tid;
        float s = 0.0f;
        #pragma unroll
        for (int w = 0; w < 8; ++w) s += POOL[w][c];
        const float p = s * (1.0f / 1024.0f);
        float s0 = wl[c] * p;
        float s1 = wl[64 + c] * p;
        float s2 = wl[128 + c] * p;
        #pragma unroll
        for (int off = 32; off > 0; off >>= 1) {
            s0 += __shfl_down(s0, off, 64);
            s1 += __shfl_down(s1, off, 64);
            s2 += __shfl_down(s2, off, 64);
        }
        if (c == 0) {
            const int n = bn & 127;
            out[(b * 3 + 0) * 128 + n] = 1.0f / (1.0f + expf(-(bl[0] + s0)));
            out[(b * 3 + 1) * 128 + n] = 1.0f / (1.0f + expf(-(bl[1] + s1)));
            out[(b * 3 + 2) * 128 + n] = 1.0f / (1.0f + expf(-(bl[2] + s2)));
        }
    }
}

extern "C" void kernel_launch(void* const* d_in, const int* in_sizes, int n_in,
                              void* d_out, int out_size, void* d_ws, size_t ws_size,
                              hipStream_t stream) {
    const float* image  = (const float*)d_in[0];
    const float* coords = (const float*)d_in[1];
    const float* w1 = (const float*)d_in[2];
    const float* b1 = (const float*)d_in[3];
    const float* w2 = (const float*)d_in[4];
    const float* b2 = (const float*)d_in[5];
    const float* w3 = (const float*)d_in[6];
    const float* b3 = (const float*)d_in[7];
    const float* w4 = (const float*)d_in[8];
    const float* b4 = (const float*)d_in[9];
    const float* w5 = (const float*)d_in[10];
    const float* b5 = (const float*)d_in[11];
    const float* wl = (const float*)d_in[12];
    const float* bl = (const float*)d_in[13];
    float* out = (float*)d_out;

    mlp_mfma_kernel<<<dim3(512), dim3(512), 0, stream>>>(
        image, coords, w1, b1, w2, b2, w3, b3, w4, b4, w5, b5, wl, bl, out);
}

// Round 4
// 134.169 us; speedup vs baseline: 2.3838x; 1.0001x over previous
//
#include <hip/hip_runtime.h>
#include <math.h>

// B=4, N=128, H=W=32, C=64.  out[b][j][n] = sigmoid(wl[j,:] . mean_hw MLP(...) + bl[j])
//
// R12: 256-THREAD BLOCKS, 32-PX TILES, FIT IN 128 VGPR.
// R11 post-mortem: 512thr/16px tiles doubled per-pixel overhead (bias reads,
// B1 build, weight ds_reads amortized over 16px not 64) and the ~132-reg
// working set spilled 48B/thread at the empirical 128-VGPR cap
// (__launch_bounds__(*,2) caps at 128 on this toolchain -- seen R9 AND R11).
// Fixes:
//   1. Back to R8's known-good shape: 256 threads / 4 waves, 2 blocks/CU.
//   2. 32 px per t-iteration (2 B-columns): acc[2][4]=32 regs, each LDS
//      weight-frag read feeds TWO MFMA columns; 8 independent acc chains
//      per layer hide MFMA latency at 2 waves/SIMD.
//   3. Bias consumed as MFMA C-operand at ks==0 (no acc init copies).
//   Working set ~120 VGPR < 128 cap -> no spill.
// Kept (proven R9-R11, passed, 0 bank conflicts): 16x16x16 layout-match
// chaining -- C/D row=(lane>>4)*4+reg == B k=(lane>>4)*4+j, acc[mt] of
// layer l IS the ks=mt B-frag of layer l+1 after in-register leaky+cvt;
// zero activation LDS traffic; weights/biases staged once into LDS.
// Tripwires: WRITE_SIZE ~KB (no spill), VGPR <= 128.

typedef float  f32x4  __attribute__((ext_vector_type(4)));
typedef f32x4  f32x4a __attribute__((may_alias));
typedef __bf16 bf16x4 __attribute__((ext_vector_type(4)));
typedef bf16x4 bf16x4a __attribute__((may_alias));
typedef short  s16x4  __attribute__((ext_vector_type(4)));

static __device__ __forceinline__ f32x4 MFMA16(bf16x4 a, bf16x4 b, f32x4 c) {
    return __builtin_amdgcn_mfma_f32_16x16x16bf16_1k(
        __builtin_bit_cast(s16x4, a), __builtin_bit_cast(s16x4, b), c, 0, 0, 0);
}

static __device__ __forceinline__ bf16x4 cvt4(f32x4 v) {
    bf16x4 r;
    r[0] = (__bf16)v[0]; r[1] = (__bf16)v[1];
    r[2] = (__bf16)v[2]; r[3] = (__bf16)v[3];
    return r;
}

__global__ __launch_bounds__(256, 2) void mlp_mfma_kernel(
    const float* __restrict__ image,   // [4,3,32,32]
    const float* __restrict__ coords,  // [4,128,2]
    const float* __restrict__ w1, const float* __restrict__ b1,   // [64,7],[64]
    const float* __restrict__ w2, const float* __restrict__ b2,   // [64,64],[64]
    const float* __restrict__ w3, const float* __restrict__ b3,
    const float* __restrict__ w4, const float* __restrict__ b4,
    const float* __restrict__ w5, const float* __restrict__ b5,
    const float* __restrict__ wl, const float* __restrict__ bl,   // [3,64],[3]
    float* __restrict__ out)           // [4,3,128]
{
    // WF: [l][frag=mt*4+ks][lane] x bf16x4  = 4*16*64*4 bf16 = 32 KB
    __shared__ __align__(16) __bf16 WF[16384];
    __shared__ __align__(16) float  POOL[4][64];     // [wave][ch]  1 KB
    __shared__ float BL[320];                        // [layer][64]

    const int tid  = threadIdx.x;
    const int wave = tid >> 6;
    const int lane = tid & 63;
    const int c15  = lane & 15;
    const int q    = lane >> 4;
    const int bn   = blockIdx.x;
    const int b    = bn >> 7;

    const float* Ws[4] = {w2, w3, w4, w5};

    // ---- stage weight A-frags (bf16) into LDS: wave w converts layer w.
    // Frag (mt,ks): lane holds W[mt*16+c15][ks*16+4q+j], j=0..3.
    {
        const float* Wsrc = Ws[wave];
        #pragma unroll
        for (int f = 0; f < 16; ++f) {
            const int mt = f >> 2, ks = f & 3;
            f32x4 v = *(const f32x4a*)(Wsrc + (mt * 16 + c15) * 64 + ks * 16 + 4 * q);
            *(bf16x4a*)&WF[((wave * 16 + f) * 64 + lane) * 4] = cvt4(v);
        }
    }
    if (tid < 64) {
        BL[tid]       = b1[tid];
        BL[64 + tid]  = b2[tid];
        BL[128 + tid] = b3[tid];
        BL[192 + tid] = b4[tid];
        BL[256 + tid] = b5[tid];
    }
    __syncthreads();

    // ---- layer-1 A-frags (K=16, channels 0..6 used): w1[row][k], k=4q+j
    bf16x4 a1[4];
    #pragma unroll
    for (int mt = 0; mt < 4; ++mt)
        #pragma unroll
        for (int j = 0; j < 4; ++j) {
            const int k = 4 * q + j;
            float v = (k < 7) ? w1[(mt * 16 + c15) * 7 + k] : 0.0f;
            a1[mt][j] = (__bf16)v;
        }

    const float cx = coords[2 * bn + 0];
    const float cy = coords[2 * bn + 1];
    const float* img = image + b * 3072;

    // ---- loop-invariant pieces of the layer-1 B-fragment.
    // Tile t = one image row (32 px): row = wave*8+t, col = ntl*16+c15.
    // B1 lane (q,c15): q=0 -> [img0,img1,img2,row], q=1 -> [col,cx,cy,0], else 0.
    const float inv31 = 1.0f / 31.0f;
    const bool  q0 = (q == 0);
    const float colf0 = (q == 1) ? (float)c15 * inv31        : 0.0f;
    const float colf1 = (q == 1) ? (float)(c15 + 16) * inv31 : 0.0f;
    const float g1 = (q == 1) ? cx : 0.0f;
    const float g2 = (q == 1) ? cy : 0.0f;

    f32x4 pool[4];
    #pragma unroll
    for (int mt = 0; mt < 4; ++mt) pool[mt] = (f32x4){0.f, 0.f, 0.f, 0.f};

    // prefetch pixels for tile 0 (hw = wave*256 + t*32 + ntl*16 + c15)
    float pc[2][3];
    #pragma unroll
    for (int ntl = 0; ntl < 2; ++ntl) {
        const int hw = wave * 256 + ntl * 16 + c15;
        pc[ntl][0] = img[hw]; pc[ntl][1] = img[1024 + hw]; pc[ntl][2] = img[2048 + hw];
    }

    #pragma unroll 1
    for (int t = 0; t < 8; ++t) {       // 8 tiles x 32 px per wave
        // ---- build layer-1 B fragments from prefetched pixels
        const float rowv = q0 ? (float)(wave * 8 + t) * inv31 : 0.0f;
        bf16x4 B1[2];
        #pragma unroll
        for (int ntl = 0; ntl < 2; ++ntl) {
            B1[ntl][0] = (__bf16)(q0 ? pc[ntl][0] : (ntl ? colf1 : colf0));
            B1[ntl][1] = (__bf16)(q0 ? pc[ntl][1] : g1);
            B1[ntl][2] = (__bf16)(q0 ? pc[ntl][2] : g2);
            B1[ntl][3] = (__bf16)rowv;
        }

        // ---- prefetch next tile's pixels
        if (t < 7) {
            #pragma unroll
            for (int ntl = 0; ntl < 2; ++ntl) {
                const int hw = wave * 256 + (t + 1) * 32 + ntl * 16 + c15;
                pc[ntl][0] = img[hw]; pc[ntl][1] = img[1024 + hw]; pc[ntl][2] = img[2048 + hw];
            }
        }

        // ======== layer 1 (bias as C operand) ========
        f32x4 acc[2][4];
        {
            f32x4 bv[4];
            #pragma unroll
            for (int mt = 0; mt < 4; ++mt)
                bv[mt] = *(const f32x4a*)&BL[mt * 16 + 4 * q];
            #pragma unroll
            for (int mt = 0; mt < 4; ++mt) {
                acc[0][mt] = MFMA16(a1[mt], B1[0], bv[mt]);
                acc[1][mt] = MFMA16(a1[mt], B1[1], bv[mt]);
            }
        }

        // ======== layers 2..5 — register-chained acts, LDS weights ========
        #pragma unroll
        for (int l = 0; l < 4; ++l) {
            // transition: leaky + cvt; acc[mt] -> B-fragment ks=mt (same lane!)
            bf16x4 Bf[2][4];
            #pragma unroll
            for (int ntl = 0; ntl < 2; ++ntl)
                #pragma unroll
                for (int mt = 0; mt < 4; ++mt) {
                    f32x4 v = acc[ntl][mt];
                    #pragma unroll
                    for (int r = 0; r < 4; ++r) v[r] = fmaxf(v[r], 0.1f * v[r]);
                    Bf[ntl][mt] = cvt4(v);
                }
            f32x4 bv[4];
            #pragma unroll
            for (int mt = 0; mt < 4; ++mt)
                bv[mt] = *(const f32x4a*)&BL[(l + 1) * 64 + mt * 16 + 4 * q];
            #pragma unroll
            for (int ks = 0; ks < 4; ++ks) {
                bf16x4 af[4];
                #pragma unroll
                for (int mt = 0; mt < 4; ++mt)
                    af[mt] = *(const bf16x4a*)
                        &WF[((l * 16 + mt * 4 + ks) * 64 + lane) * 4];
                #pragma unroll
                for (int mt = 0; mt < 4; ++mt) {
                    acc[0][mt] = MFMA16(af[mt], Bf[0][ks],
                                        (ks == 0) ? bv[mt] : acc[0][mt]);
                    acc[1][mt] = MFMA16(af[mt], Bf[1][ks],
                                        (ks == 0) ? bv[mt] : acc[1][mt]);
                }
            }
        }

        // ---- final leaky + pool accumulate (registers only)
        #pragma unroll
        for (int ntl = 0; ntl < 2; ++ntl)
            #pragma unroll
            for (int mt = 0; mt < 4; ++mt)
                #pragma unroll
                for (int r = 0; r < 4; ++r) {
                    const float v = acc[ntl][mt][r];
                    pool[mt][r] += fmaxf(v, 0.1f * v);
                }
    }

    // ---- in-wave pre-reduce over the 16 pixel-columns (c15 bits 0..3)
    #pragma unroll
    for (int mt = 0; mt < 4; ++mt)
        #pragma unroll
        for (int r = 0; r < 4; ++r) {
            float v = pool[mt][r];
            v += __shfl_xor(v, 1, 64);
            v += __shfl_xor(v, 2, 64);
            v += __shfl_xor(v, 4, 64);
            v += __shfl_xor(v, 8, 64);
            pool[mt][r] = v;
        }
    if (c15 == 0) {
        #pragma unroll
        for (int mt = 0; mt < 4; ++mt)
            *(f32x4a*)&POOL[wave][mt * 16 + 4 * q] = pool[mt];
    }

    __syncthreads();

    // ---- block reduce (4 waves) + head + sigmoid
    if (tid < 64) {
        const int c = tid;
        float s = 0.0f;
        #pragma unroll
        for (int w = 0; w < 4; ++w) s += POOL[w][c];
        const float p = s * (1.0f / 1024.0f);
        float s0 = wl[c] * p;
        float s1 = wl[64 + c] * p;
        float s2 = wl[128 + c] * p;
        #pragma unroll
        for (int off = 32; off > 0; off >>= 1) {
            s0 += __shfl_down(s0, off, 64);
            s1 += __shfl_down(s1, off, 64);
            s2 += __shfl_down(s2, off, 64);
        }
        if (c == 0) {
            const int n = bn & 127;
            out[(b * 3 + 0) * 128 + n] = 1.0f / (1.0f + expf(-(bl[0] + s0)));
            out[(b * 3 + 1) * 128 + n] = 1.0f / (1.0f + expf(-(bl[1] + s1)));
            out[(b * 3 + 2) * 128 + n] = 1.0f / (1.0f + expf(-(bl[2] + s2)));
        }
    }
}

extern "C" void kernel_launch(void* const* d_in, const int* in_sizes, int n_in,
                              void* d_out, int out_size, void* d_ws, size_t ws_size,
                              hipStream_t stream) {
    const float* image  = (const float*)d_in[0];
    const float* coords = (const float*)d_in[1];
    const float* w1 = (const float*)d_in[2];
    const float* b1 = (const float*)d_in[3];
    const float* w2 = (const float*)d_in[4];
    const float* b2 = (const float*)d_in[5];
    const float* w3 = (const float*)d_in[6];
    const float* b3 = (const float*)d_in[7];
    const float* w4 = (const float*)d_in[8];
    const float* b4 = (const float*)d_in[9];
    const float* w5 = (const float*)d_in[10];
    const float* b5 = (const float*)d_in[11];
    const float* wl = (const float*)d_in[12];
    const float* bl = (const float*)d_in[13];
    float* out = (float*)d_out;

    mlp_mfma_kernel<<<dim3(512), dim3(256), 0, stream>>>(
        image, coords, w1, b1, w2, b2, w3, b3, w4, b4, w5, b5, wl, bl, out);
}

// Round 5
// 128.271 us; speedup vs baseline: 2.4934x; 1.0460x over previous
//
#include <hip/hip_runtime.h>
#include <math.h>

// B=4, N=128, H=W=32, C=64.  out[b][j][n] = sigmoid(wl[j,:] . mean_hw MLP(...) + bl[j])
//
// R13: SINGLE-COLUMN TILES + NO RUNTIME-INDEXED ARRAYS -> REAL VGPR SLACK.
// R9/R11/R12 post-mortem: every variant pinned VGPR at exactly 128 and
// spilled (WRITE 13/12.7/35 MB scratch). At the cap the allocator spills
// the LONGEST-LIVED values: pool[4] (whole-kernel range -> scratch RMW in
// every tile iteration = the latency bottleneck; MfmaUtil 19/VALU 31/Occ 19,
// nothing saturated) and Ws[4] (runtime-indexed pointer array = guaranteed
// scratch). Estimating "~120 < 128" three times was the repeated mistake;
// this round targets ~95 peak:
//   1. ONE B-column per tile (16 px): acc[4]=16, Bf[4]=8 regs (was 32+16).
//   2. Ws[4] runtime index -> wave-uniform ternary (s_cselect, no scratch).
//   3. Shape back to proven R8: 256 thr / 4 waves, grid 512, lb(256,2).
// Kept (proven R9-R12, passed 4x, 0 bank conflicts): 16x16x16 layout-match
// chaining -- C/D row=(lane>>4)*4+reg == B k=(lane>>4)*4+j, acc[mt] of
// layer l IS the ks=mt B-frag of layer l+1 after in-register leaky+cvt;
// zero activation LDS traffic; weights/biases staged once into LDS; bias
// as MFMA C-operand at ks==0; pixels prefetched one tile ahead.
// Tripwires: WRITE_SIZE ~KB; VGPR strictly < 128 (if ==128 again, the
// allocator is still clamping and the next cut is pool->LDS).

typedef float  f32x4  __attribute__((ext_vector_type(4)));
typedef f32x4  f32x4a __attribute__((may_alias));
typedef __bf16 bf16x4 __attribute__((ext_vector_type(4)));
typedef bf16x4 bf16x4a __attribute__((may_alias));
typedef short  s16x4  __attribute__((ext_vector_type(4)));

static __device__ __forceinline__ f32x4 MFMA16(bf16x4 a, bf16x4 b, f32x4 c) {
    return __builtin_amdgcn_mfma_f32_16x16x16bf16_1k(
        __builtin_bit_cast(s16x4, a), __builtin_bit_cast(s16x4, b), c, 0, 0, 0);
}

static __device__ __forceinline__ bf16x4 cvt4(f32x4 v) {
    bf16x4 r;
    r[0] = (__bf16)v[0]; r[1] = (__bf16)v[1];
    r[2] = (__bf16)v[2]; r[3] = (__bf16)v[3];
    return r;
}

__global__ __launch_bounds__(256, 2) void mlp_mfma_kernel(
    const float* __restrict__ image,   // [4,3,32,32]
    const float* __restrict__ coords,  // [4,128,2]
    const float* __restrict__ w1, const float* __restrict__ b1,   // [64,7],[64]
    const float* __restrict__ w2, const float* __restrict__ b2,   // [64,64],[64]
    const float* __restrict__ w3, const float* __restrict__ b3,
    const float* __restrict__ w4, const float* __restrict__ b4,
    const float* __restrict__ w5, const float* __restrict__ b5,
    const float* __restrict__ wl, const float* __restrict__ bl,   // [3,64],[3]
    float* __restrict__ out)           // [4,3,128]
{
    // WF: [l][frag=mt*4+ks][lane] x bf16x4  = 4*16*64*4 bf16 = 32 KB
    __shared__ __align__(16) __bf16 WF[16384];
    __shared__ __align__(16) float  POOL[4][64];     // [wave][ch]  1 KB
    __shared__ float BL[320];                        // [layer][64]

    const int tid  = threadIdx.x;
    const int wave = tid >> 6;
    const int lane = tid & 63;
    const int c15  = lane & 15;
    const int q    = lane >> 4;
    const int bn   = blockIdx.x;
    const int b    = bn >> 7;

    // ---- stage weight A-frags (bf16) into LDS: wave w converts layer w.
    // NO runtime-indexed array (scratch hazard): wave-uniform ternary.
    {
        const float* Wsrc = (wave == 0) ? w2 : (wave == 1) ? w3
                          : (wave == 2) ? w4 : w5;
        #pragma unroll
        for (int f = 0; f < 16; ++f) {
            const int mt = f >> 2, ks = f & 3;
            f32x4 v = *(const f32x4a*)(Wsrc + (mt * 16 + c15) * 64 + ks * 16 + 4 * q);
            *(bf16x4a*)&WF[((wave * 16 + f) * 64 + lane) * 4] = cvt4(v);
        }
    }
    if (tid < 64) {
        BL[tid]       = b1[tid];
        BL[64 + tid]  = b2[tid];
        BL[128 + tid] = b3[tid];
        BL[192 + tid] = b4[tid];
        BL[256 + tid] = b5[tid];
    }
    __syncthreads();

    // ---- layer-1 A-frags (K=16, channels 0..6 used): w1[row][k], k=4q+j
    bf16x4 a1[4];
    #pragma unroll
    for (int mt = 0; mt < 4; ++mt)
        #pragma unroll
        for (int j = 0; j < 4; ++j) {
            const int k = 4 * q + j;
            float v = (k < 7) ? w1[(mt * 16 + c15) * 7 + k] : 0.0f;
            a1[mt][j] = (__bf16)v;
        }

    const float cx = coords[2 * bn + 0];
    const float cy = coords[2 * bn + 1];
    const float* img = image + b * 3072;

    // ---- loop-invariant pieces of the layer-1 B-fragment.
    // Wave pixels: hw = wave*256 + t*16 + c15, t=0..15.
    // row = wave*8 + (t>>1); col = (t&1)*16 + c15.
    // B1 lane (q,c15): q=0 -> [img0,img1,img2,row], q=1 -> [col,cx,cy,0], else 0.
    const float inv31 = 1.0f / 31.0f;
    const bool  q0  = (q == 0);
    const float g0e = (q == 1) ? (float)c15 * inv31        : 0.0f;
    const float g0o = (q == 1) ? (float)(c15 + 16) * inv31 : 0.0f;
    const float g1  = (q == 1) ? cx : 0.0f;
    const float g2  = (q == 1) ? cy : 0.0f;

    f32x4 pool[4];
    #pragma unroll
    for (int mt = 0; mt < 4; ++mt) pool[mt] = (f32x4){0.f, 0.f, 0.f, 0.f};

    // prefetch pixels for tile 0
    float p0, p1, p2;
    {
        const int hw = wave * 256 + c15;
        p0 = img[hw]; p1 = img[1024 + hw]; p2 = img[2048 + hw];
    }

    #pragma unroll 1
    for (int t = 0; t < 16; ++t) {      // 16 tiles x 16 px per wave
        // ---- build layer-1 B fragment from prefetched pixels
        const float rowv = (float)(wave * 8 + (t >> 1)) * inv31;
        bf16x4 B1;
        B1[0] = (__bf16)(q0 ? p0 : ((t & 1) ? g0o : g0e));
        B1[1] = (__bf16)(q0 ? p1 : g1);
        B1[2] = (__bf16)(q0 ? p2 : g2);
        B1[3] = (__bf16)(q0 ? rowv : 0.0f);

        // ---- prefetch next tile's pixels
        {
            const int tt = (t < 15) ? (t + 1) : 15;
            const int hw = wave * 256 + tt * 16 + c15;
            p0 = img[hw]; p1 = img[1024 + hw]; p2 = img[2048 + hw];
        }

        // ======== layer 1 (bias as C operand) ========
        f32x4 acc[4];
        {
            f32x4 bv[4];
            #pragma unroll
            for (int mt = 0; mt < 4; ++mt)
                bv[mt] = *(const f32x4a*)&BL[mt * 16 + 4 * q];
            #pragma unroll
            for (int mt = 0; mt < 4; ++mt)
                acc[mt] = MFMA16(a1[mt], B1, bv[mt]);
        }

        // ======== layers 2..5 — register-chained acts, LDS weights ========
        #pragma unroll
        for (int l = 0; l < 4; ++l) {
            // transition: leaky + cvt; acc[mt] -> B-fragment ks=mt (same lane!)
            bf16x4 Bf[4];
            #pragma unroll
            for (int mt = 0; mt < 4; ++mt) {
                f32x4 v = acc[mt];
                #pragma unroll
                for (int r = 0; r < 4; ++r) v[r] = fmaxf(v[r], 0.1f * v[r]);
                Bf[mt] = cvt4(v);
            }
            f32x4 bv[4];
            #pragma unroll
            for (int mt = 0; mt < 4; ++mt)
                bv[mt] = *(const f32x4a*)&BL[(l + 1) * 64 + mt * 16 + 4 * q];
            #pragma unroll
            for (int ks = 0; ks < 4; ++ks) {
                bf16x4 af[4];
                #pragma unroll
                for (int mt = 0; mt < 4; ++mt)
                    af[mt] = *(const bf16x4a*)
                        &WF[((l * 16 + mt * 4 + ks) * 64 + lane) * 4];
                #pragma unroll
                for (int mt = 0; mt < 4; ++mt)
                    acc[mt] = MFMA16(af[mt], Bf[ks],
                                     (ks == 0) ? bv[mt] : acc[mt]);
            }
        }

        // ---- final leaky + pool accumulate (registers only)
        #pragma unroll
        for (int mt = 0; mt < 4; ++mt)
            #pragma unroll
            for (int r = 0; r < 4; ++r) {
                const float v = acc[mt][r];
                pool[mt][r] += fmaxf(v, 0.1f * v);
            }
    }

    // ---- in-wave pre-reduce over the 16 pixel-columns (c15 bits 0..3)
    #pragma unroll
    for (int mt = 0; mt < 4; ++mt)
        #pragma unroll
        for (int r = 0; r < 4; ++r) {
            float v = pool[mt][r];
            v += __shfl_xor(v, 1, 64);
            v += __shfl_xor(v, 2, 64);
            v += __shfl_xor(v, 4, 64);
            v += __shfl_xor(v, 8, 64);
            pool[mt][r] = v;
        }
    if (c15 == 0) {
        #pragma unroll
        for (int mt = 0; mt < 4; ++mt)
            *(f32x4a*)&POOL[wave][mt * 16 + 4 * q] = pool[mt];
    }

    __syncthreads();

    // ---- block reduce (4 waves) + head + sigmoid
    if (tid < 64) {
        const int c = tid;
        float s = 0.0f;
        #pragma unroll
        for (int w = 0; w < 4; ++w) s += POOL[w][c];
        const float p = s * (1.0f / 1024.0f);
        float s0 = wl[c] * p;
        float s1 = wl[64 + c] * p;
        float s2 = wl[128 + c] * p;
        #pragma unroll
        for (int off = 32; off > 0; off >>= 1) {
            s0 += __shfl_down(s0, off, 64);
            s1 += __shfl_down(s1, off, 64);
            s2 += __shfl_down(s2, off, 64);
        }
        if (c == 0) {
            const int n = bn & 127;
            out[(b * 3 + 0) * 128 + n] = 1.0f / (1.0f + expf(-(bl[0] + s0)));
            out[(b * 3 + 1) * 128 + n] = 1.0f / (1.0f + expf(-(bl[1] + s1)));
            out[(b * 3 + 2) * 128 + n] = 1.0f / (1.0f + expf(-(bl[2] + s2)));
        }
    }
}

extern "C" void kernel_launch(void* const* d_in, const int* in_sizes, int n_in,
                              void* d_out, int out_size, void* d_ws, size_t ws_size,
                              hipStream_t stream) {
    const float* image  = (const float*)d_in[0];
    const float* coords = (const float*)d_in[1];
    const float* w1 = (const float*)d_in[2];
    const float* b1 = (const float*)d_in[3];
    const float* w2 = (const float*)d_in[4];
    const float* b2 = (const float*)d_in[5];
    const float* w3 = (const float*)d_in[6];
    const float* b3 = (const float*)d_in[7];
    const float* w4 = (const float*)d_in[8];
    const float* b4 = (const float*)d_in[9];
    const float* w5 = (const float*)d_in[10];
    const float* b5 = (const float*)d_in[11];
    const float* wl = (const float*)d_in[12];
    const float* bl = (const float*)d_in[13];
    float* out = (float*)d_out;

    mlp_mfma_kernel<<<dim3(512), dim3(256), 0, stream>>>(
        image, coords, w1, b1, w2, b2, w3, b3, w4, b4, w5, b5, wl, bl, out);
}